// Round 11
// baseline (218.964 us; speedup 1.0000x reference)
//
#include <hip/hip_runtime.h>

#define S_LEN 2048
#define D_DIM 128
#define NBH   32
#define LOG2E 1.44269504f
#define NEGM  -1000000.0f

typedef __bf16 bf16x8 __attribute__((ext_vector_type(8)));
typedef short  s16x8  __attribute__((ext_vector_type(8)));
typedef float  f32x4  __attribute__((ext_vector_type(4)));
typedef float  f32x16 __attribute__((ext_vector_type(16)));
typedef unsigned int u32x4 __attribute__((ext_vector_type(4)));
typedef unsigned int u32x2 __attribute__((ext_vector_type(2)));

static __device__ __forceinline__ unsigned short f32_to_bf16_bits_exact(float f) {
    return (unsigned short)(__float_as_uint(f) >> 16);   // exact for small ints
}
static __device__ __forceinline__ float round_away(float t) {
    float r = floorf(fabsf(t) + 0.5f);
    return (t >= 0.0f) ? r : -r;
}
// p0,p1 -> one u32 of two bf16(floor(fma(p,127,0.5))) via v_perm
static __device__ __forceinline__ unsigned int pq_pack(float p0, float p1) {
    float a = floorf(fmaf(p0, 127.0f, 0.5f));
    float b = floorf(fmaf(p1, 127.0f, 0.5f));
    return __builtin_amdgcn_perm(__float_as_uint(b), __float_as_uint(a), 0x07060302);
}

// ------- fused: per-token quant of K (blocks 0..8191) + V amax (8192..) ----
__global__ __launch_bounds__(256) void quant_kv_kernel(
    const float* __restrict__ k, const float* __restrict__ v,
    unsigned short* __restrict__ kq, float* __restrict__ ks,
    unsigned int* __restrict__ vab)
{
    if (blockIdx.x < 8192) {
        int row = blockIdx.x * 8 + (threadIdx.x >> 5);
        int l32 = threadIdx.x & 31;
        size_t base = (size_t)row * D_DIM + l32 * 4;
        float4 x = *(const float4*)(k + base);
        float amax = fmaxf(fmaxf(fabsf(x.x), fabsf(x.y)), fmaxf(fabsf(x.z), fabsf(x.w)));
        #pragma unroll
        for (int m = 1; m < 32; m <<= 1) amax = fmaxf(amax, __shfl_xor(amax, m));
        float scale = fmaxf(amax, 1e-8f) / 127.0f;
        ushort4 o;
        o.x = f32_to_bf16_bits_exact(fminf(fmaxf(round_away(x.x / scale), -127.0f), 127.0f));
        o.y = f32_to_bf16_bits_exact(fminf(fmaxf(round_away(x.y / scale), -127.0f), 127.0f));
        o.z = f32_to_bf16_bits_exact(fminf(fmaxf(round_away(x.z / scale), -127.0f), 127.0f));
        o.w = f32_to_bf16_bits_exact(fminf(fmaxf(round_away(x.w / scale), -127.0f), 127.0f));
        *(ushort4*)(kq + base) = o;
        if (l32 == 0) ks[row] = scale;
    } else {
        int bid2 = blockIdx.x - 8192;
        int bh = bid2 >> 3, blk = bid2 & 7;
        const float4* base = (const float4*)(v + (size_t)bh * S_LEN * D_DIM) + blk * 8192;
        int t = threadIdx.x;
        float am = 0.0f;
        #pragma unroll
        for (int i = 0; i < 32; ++i) {
            float4 x = base[t + i * 256];
            am = fmaxf(am, fmaxf(fmaxf(fabsf(x.x), fabsf(x.y)), fmaxf(fabsf(x.z), fabsf(x.w))));
        }
        #pragma unroll
        for (int m = 1; m < 64; m <<= 1) am = fmaxf(am, __shfl_xor(am, m));
        __shared__ float red[4];
        if ((t & 63) == 0) red[t >> 6] = am;
        __syncthreads();
        if (t == 0) {
            float a = fmaxf(fmaxf(red[0], red[1]), fmaxf(red[2], red[3]));
            atomicMax(&vab[bh], __float_as_uint(a));
        }
    }
}

// ---------------- V quantize + transpose to [B,H,D,S] ----------------------
__global__ __launch_bounds__(256) void vtq_kernel(const float* __restrict__ v,
                                                  const unsigned int* __restrict__ vab,
                                                  unsigned short* __restrict__ vT)
{
    __shared__ unsigned short tileT[128][72];
    int bh = blockIdx.x >> 5, sb = blockIdx.x & 31;
    float scale = fmaxf(__uint_as_float(vab[bh]), 1e-8f) / 127.0f;
    int t = threadIdx.x;
    const float* src = v + ((size_t)bh * S_LEN + sb * 64) * D_DIM;
    #pragma unroll
    for (int it = 0; it < 8; ++it) {
        int c = t + it * 256;
        int rs = c >> 5, c4 = (c & 31) * 4;
        float4 x = *(const float4*)(src + rs * D_DIM + c4);
        float vals[4] = {x.x, x.y, x.z, x.w};
        #pragma unroll
        for (int u = 0; u < 4; ++u) {
            float r = fminf(fmaxf(round_away(vals[u] / scale), -127.0f), 127.0f);
            tileT[c4 + u][rs] = f32_to_bf16_bits_exact(r);
        }
    }
    __syncthreads();
    unsigned short* dst = vT + (size_t)bh * D_DIM * S_LEN + sb * 64;
    #pragma unroll
    for (int it = 0; it < 4; ++it) {
        int c = t + it * 256;
        int d = c >> 3, c8 = (c & 7) * 8;
        *(s16x8*)(dst + (size_t)d * S_LEN + c8) = *(const s16x8*)&tileT[d][c8];
    }
}

// -------- int8 flash attention: key-split chunks + deterministic merge -----
// Grid 736 WGs, LPT order. qb<=8 whole; qb in [9,15] split into 2 chunks of
// (qb+1) key-tiles. Chunk0 -> U0 in out rows; chunk1 -> U1 in ws; second
// finisher (device ticket) merges with fixed operand order (deterministic).
__global__ __launch_bounds__(512, 4) void attn_kernel(
    const float* __restrict__ qsrc,
    const unsigned short* __restrict__ kq,
    const unsigned short* __restrict__ vT,
    const float* __restrict__ ks,
    const unsigned int* __restrict__ vab,
    const float* __restrict__ smp,
    float* __restrict__ out,
    float* __restrict__ U1,
    float2* __restrict__ mlbuf,
    unsigned int* __restrict__ tickets)
{
    extern __shared__ char smem[];

    const int tid  = threadIdx.x;
    const int lane = tid & 63;
    const int wid  = tid >> 6;       // 0..7
    const int w4   = wid & 3;
    const int half = wid >> 2;       // key-column half
    const int c32  = lane & 31;
    const int hi   = lane >> 5;
    const int t8   = tid & 255;

    char*   KbH  = smem + half * 8192;
    char*   VbH  = smem + 16384 + half * 8192;
    float*  ksl  = (float*)(smem + 32768);
    float2* ML   = (float2*)(smem + 34816);   // used only AFTER the K-loop
    char*   Qlds = smem + 40960;
    float*  Ol   = (float*)smem;

    // ---- LPT schedule decode: lengths desc (18,16,15,...,2) ----
    int rem = (int)blockIdx.x, qb = 0, chunk = -1, bh = 0;
    {
        bool fnd = false;
        for (int L = 18; L >= 2 && !fnd; --L) {
            if (L >= 10 && L <= 16) {                 // chunk entries, qb = L-1
                if (rem < 64) { qb = L - 1; chunk = rem >> 5; bh = rem & 31; fnd = true; }
                else rem -= 64;
            }
            if (!fnd && !(L & 1)) {                   // unsplit entries, jn = L
                int qu = (L >> 1) - 1;
                if (qu <= 8) {
                    if (rem < 32) { qb = qu; chunk = -1; bh = rem & 31; fnd = true; }
                    else rem -= 32;
                }
            }
        }
    }
    int j0 = 0, jEnd = 2 * qb + 2;
    if (chunk == 0) jEnd = qb + 1;
    else if (chunk == 1) j0 = qb + 1;
    const int pair = (qb - 9) * 32 + bh;              // valid when chunk >= 0

    const float qk_scale = smp[0] * LOG2E;
    const float vscale   = fmaxf(__uint_as_float(vab[bh]), 1e-8f) / 127.0f;
    const float vs_term  = vscale / 127.0f;

    const char* kqb = (const char*)(kq + (size_t)bh * S_LEN * D_DIM);
    const char* vtb = (const char*)(vT + (size_t)bh * D_DIM * S_LEN);

    // ---- prologue: ks row + in-kernel Q quantization into Qlds ----
    // qsl lives in the Kb region (smem+0): prologue-only, consumed into the
    // qf register before the loop's first barrier (after which Kb is reused).
    ((f32x4*)ksl)[tid] = ((const f32x4*)(ks + (size_t)bh * S_LEN))[tid];
    float* qsl = (float*)smem;
    {
        const float* qg = qsrc + ((size_t)bh * S_LEN + qb * 128) * D_DIM;
        int l32 = tid & 31;
        #pragma unroll
        for (int p = 0; p < 8; ++p) {
            int row = p * 16 + (tid >> 5);
            f32x4 x = *(const f32x4*)(qg + (size_t)row * D_DIM + l32 * 4);
            float am = fmaxf(fmaxf(fabsf(x[0]), fabsf(x[1])), fmaxf(fabsf(x[2]), fabsf(x[3])));
            #pragma unroll
            for (int m = 1; m < 32; m <<= 1) am = fmaxf(am, __shfl_xor(am, m));
            float scale = fmaxf(am, 1e-8f) / 127.0f;
            if (l32 == 0) qsl[row] = scale;
            unsigned short b0 = f32_to_bf16_bits_exact(fminf(fmaxf(round_away(x[0] / scale), -127.0f), 127.0f));
            unsigned short b1 = f32_to_bf16_bits_exact(fminf(fmaxf(round_away(x[1] / scale), -127.0f), 127.0f));
            unsigned short b2 = f32_to_bf16_bits_exact(fminf(fmaxf(round_away(x[2] / scale), -127.0f), 127.0f));
            unsigned short b3 = f32_to_bf16_bits_exact(fminf(fmaxf(round_away(x[3] / scale), -127.0f), 127.0f));
            u32x2 pk; pk.x = (unsigned int)b0 | ((unsigned int)b1 << 16);
            pk.y = (unsigned int)b2 | ((unsigned int)b3 << 16);
            int base = (row & 3) * 8192 + (row >> 2) * 256;
            int off  = (l32 * 8) ^ (((row >> 2) & 15) << 4);
            *(u32x2*)(Qlds + base + off) = pk;
        }
    }
    __syncthreads();
    const int   q  = qb * 128 + c32 * 4 + w4;
    const float qf = qsl[c32 * 4 + w4] * qk_scale;   // register before first B1

    // per-thread staging offsets (constant over j): linear LDS, pre-swz global
    int kOff[2], vOff[2], lOff[2];
    #pragma unroll
    for (int it = 0; it < 2; ++it) {
        int L = (t8 + it * 256) * 16;
        lOff[it] = L;
        int r = L >> 8, x = L & 255;
        int c = x ^ ((r & 15) << 4);
        kOff[it] = (half * 32 + r) * 256 + c;
        vOff[it] = ((c >> 6) * 32 + r) * (S_LEN * 2) + half * 64 + (c & 63);
    }

    float mrow = -100.0f;            // finite sentinel; real scores are O(1)
    float lrow = 0.0f;
    f32x16 oacc0, oacc1, oacc2, oacc3;
    #pragma unroll
    for (int i = 0; i < 16; ++i) { oacc0[i] = 0.f; oacc1[i] = 0.f; oacc2[i] = 0.f; oacc3[i] = 0.f; }

    const int swz = (c32 & 15) << 4;
    const char* aBase = KbH + c32 * 256;
    const char* bBase = Qlds + w4 * 8192 + c32 * 256;
    const char* vBase = VbH + c32 * 256;

    for (int j = j0; j < jEnd; ++j) {
        const int jb = j * 64;
        s16x8 kr0 = *(const s16x8*)(kqb + jb * 256 + kOff[0]);
        s16x8 kr1 = *(const s16x8*)(kqb + jb * 256 + kOff[1]);
        s16x8 vr0 = *(const s16x8*)(vtb + jb * 2   + vOff[0]);
        s16x8 vr1 = *(const s16x8*)(vtb + jb * 2   + vOff[1]);
        __syncthreads();                 // B1: previous tile's readers done
        *(s16x8*)(KbH + lOff[0]) = kr0;
        *(s16x8*)(KbH + lOff[1]) = kr1;
        *(s16x8*)(VbH + lOff[0]) = vr0;
        *(s16x8*)(VbH + lOff[1]) = vr1;
        __syncthreads();                 // B2: tile ready

        // ---- swapped QK^T: S^T = K_half · Q^T ----
        f32x16 sc;
        #pragma unroll
        for (int i = 0; i < 16; ++i) sc[i] = 0.f;
        #pragma unroll
        for (int st = 0; st < 8; ++st) {
            int cB = (st * 32 + hi * 16) ^ swz;
            bf16x8 a = __builtin_bit_cast(bf16x8, *(const s16x8*)(aBase + cB));
            bf16x8 b = __builtin_bit_cast(bf16x8, *(const s16x8*)(bBase + cB));
            sc = __builtin_amdgcn_mfma_f32_32x32x16_bf16(a, b, sc, 0, 0, 0);
        }

        // ---- dequant folded with -mrow: t = fma(s_int, qf*kv, -mrow) ----
        const int  jbh = jb + half * 32;
        const bool need_mask = (jbh + 31 > qb * 128 + w4);
        float mhA = -3.0e38f, mhB = -3.0e38f;
        #pragma unroll
        for (int gg = 0; gg < 4; ++gg) {
            f32x4 kv = *(const f32x4*)&ksl[jbh + gg * 8 + hi * 4];
            #pragma unroll
            for (int i = 0; i < 4; ++i) {
                int r = gg * 4 + i;
                float c  = qf * kv[i];
                float tv = fmaf(sc[r], c, -mrow);
                if (need_mask) tv = (q >= jbh + gg * 8 + i + hi * 4) ? tv : NEGM;
                sc[r] = tv;
                if (i & 1) mhB = fmaxf(mhB, tv);
                else       mhA = fmaxf(mhA, tv);
            }
        }
        float mh     = fmaxf(mhA, mhB);
        float vmax_t = fmaxf(mh, __shfl_xor(mh, 32));

        // ---- defer-max (THR=1): rescale only when row max grew by > 1 ----
        if (__any(vmax_t > 1.0f)) {
            float sh    = fmaxf(vmax_t, 0.0f);
            float alpha = exp2f(-sh);
            mrow += sh;
            #pragma unroll
            for (int r = 0; r < 16; ++r) sc[r] -= sh;
            oacc0 *= alpha; oacc1 *= alpha; oacc2 *= alpha; oacc3 *= alpha;
            lrow  *= alpha;
        }

        // ---- p = exp2(t) in place (p <= 2, p_q <= 254: bf16-exact) ----
        float ts[8];
        #pragma unroll
        for (int r = 0; r < 8; ++r) {
            sc[r]     = exp2f(sc[r]);
            sc[r + 8] = exp2f(sc[r + 8]);
            ts[r] = sc[r] + sc[r + 8];
        }
        #pragma unroll
        for (int stp = 4; stp >= 1; stp >>= 1)
            #pragma unroll
            for (int r = 0; r < stp; ++r) ts[r] += ts[r + stp];
        lrow += ts[0] + __shfl_xor(ts[0], 32);

        // ---- pack p_q (bf16), cross-half swap, PV: 8 MFMA ----
        unsigned int W[8];
        #pragma unroll
        for (int gg = 0; gg < 4; ++gg) {
            W[gg*2+0] = pq_pack(sc[gg*4+0], sc[gg*4+1]);
            W[gg*2+1] = pq_pack(sc[gg*4+2], sc[gg*4+3]);
        }
        #pragma unroll
        for (int s = 0; s < 2; ++s) {
            asm("v_permlane32_swap_b32 %0, %1" : "+v"(W[s*4+0]), "+v"(W[s*4+2]));
            asm("v_permlane32_swap_b32 %0, %1" : "+v"(W[s*4+1]), "+v"(W[s*4+3]));
        }
        #pragma unroll
        for (int s = 0; s < 2; ++s) {
            u32x4 uw; uw.x = W[s*4+0]; uw.y = W[s*4+1]; uw.z = W[s*4+2]; uw.w = W[s*4+3];
            bf16x8 bfrag = __builtin_bit_cast(bf16x8, uw);
            int cb = s * 32 + hi * 16;
            bf16x8 va;
            va = __builtin_bit_cast(bf16x8, *(const s16x8*)(vBase + ((cb +   0) ^ swz)));
            oacc0 = __builtin_amdgcn_mfma_f32_32x32x16_bf16(va, bfrag, oacc0, 0, 0, 0);
            va = __builtin_bit_cast(bf16x8, *(const s16x8*)(vBase + ((cb +  64) ^ swz)));
            oacc1 = __builtin_amdgcn_mfma_f32_32x32x16_bf16(va, bfrag, oacc1, 0, 0, 0);
            va = __builtin_bit_cast(bf16x8, *(const s16x8*)(vBase + ((cb + 128) ^ swz)));
            oacc2 = __builtin_amdgcn_mfma_f32_32x32x16_bf16(va, bfrag, oacc2, 0, 0, 0);
            va = __builtin_bit_cast(bf16x8, *(const s16x8*)(vBase + ((cb + 192) ^ swz)));
            oacc3 = __builtin_amdgcn_mfma_f32_32x32x16_bf16(va, bfrag, oacc3, 0, 0, 0);
        }
    }

    // ---- merge the two key-halves: exchange (m, l) via LDS ----
    __syncthreads();
    if (hi == 0) { float2 ml2; ml2.x = mrow; ml2.y = lrow; ML[half * 128 + w4 * 32 + c32] = ml2; }
    __syncthreads();
    float2 mo  = ML[(1 - half) * 128 + w4 * 32 + c32];
    float  mfin = fmaxf(mrow, mo.x);
    float  bs  = exp2f(mrow - mfin);       // own scale (~0 if this half all-masked)
    float  bo  = exp2f(mo.x - mfin);
    float  lfin = lrow * bs + mo.y * bo;

    // chunk partial bookkeeping: per-row (m, l), written once (half0, hi0)
    if (chunk >= 0 && half == 0 && hi == 0) {
        float2 t; t.x = mfin; t.y = lfin;
        mlbuf[(size_t)pair * 256 + chunk * 128 + (c32 * 4 + w4)] = t;
    }

    const float inv = (chunk < 0) ? (bs * vs_term / lfin) : bs;
    float* dstBase = (chunk == 1) ? (U1 + (size_t)pair * 16384)
                                  : (out + ((size_t)bh * S_LEN + qb * 128) * D_DIM);

    // ---- epilogue: O^T -> LDS transpose -> coalesced stores ----
    for (int pass = 0; pass < 2; ++pass) {
        __syncthreads();
        if (half == 0 && (w4 >> 1) == pass) {
            float* reg = Ol + (w4 & 1) * 4224 + c32 * 132;
            #pragma unroll
            for (int r = 0; r < 16; ++r) {
                int drow = (r & 3) + 8 * (r >> 2) + 4 * hi;
                reg[drow]      = oacc0[r] * inv;
                reg[drow + 32] = oacc1[r] * inv;
                reg[drow + 64] = oacc2[r] * inv;
                reg[drow + 96] = oacc3[r] * inv;
            }
        }
        __syncthreads();
        if (half == 1 && (w4 >> 1) == pass) {
            float* reg = Ol + (w4 & 1) * 4224 + c32 * 132;
            #pragma unroll
            for (int r = 0; r < 16; ++r) {
                int drow = (r & 3) + 8 * (r >> 2) + 4 * hi;
                reg[drow]      += oacc0[r] * inv;
                reg[drow + 32] += oacc1[r] * inv;
                reg[drow + 64] += oacc2[r] * inv;
                reg[drow + 96] += oacc3[r] * inv;
            }
        }
        __syncthreads();
        #pragma unroll
        for (int it = 0; it < 4; ++it) {
            int idx = tid + it * 512;
            int w2  = idx >> 10;
            int rem2 = idx & 1023;
            int row = rem2 >> 5, c4 = rem2 & 31;
            f32x4 v4 = *(const f32x4*)(Ol + w2 * 4224 + row * 132 + c4 * 4);
            int lr = row * 4 + pass * 2 + w2;
            *(f32x4*)(dstBase + (size_t)lr * D_DIM + c4 * 4) = v4;
        }
    }

    // ---- split pairs: ticket; second finisher merges (fixed operand order) ----
    if (chunk >= 0) {
        __syncthreads();
        int* flg = (int*)(smem + 34816);
        if (tid == 0) {
            __threadfence();
            unsigned int old = __hip_atomic_fetch_add(&tickets[pair], 1u,
                                 __ATOMIC_ACQ_REL, __HIP_MEMORY_SCOPE_AGENT);
            flg[0] = (int)old;
        }
        __syncthreads();
        if (flg[0] == 1) {
            __threadfence();
            const float2* mp = mlbuf + (size_t)pair * 256;
            float* orows = out + ((size_t)bh * S_LEN + qb * 128) * D_DIM;
            const float* U1p = U1 + (size_t)pair * 16384;
            #pragma unroll
            for (int it = 0; it < 8; ++it) {
                int vec = tid + it * 512;          // 4096 f32x4 = 128 x 128
                int row = vec >> 5;
                float2 a = mp[row], b = mp[128 + row];
                float ms = fmaxf(a.x, b.x);
                float w0 = exp2f(a.x - ms), w1 = exp2f(b.x - ms);
                float scl = vs_term / (w0 * a.y + w1 * b.y);
                f32x4 u0 = ((const f32x4*)orows)[vec];
                f32x4 u1 = ((const f32x4*)U1p)[vec];
                f32x4 r;
                #pragma unroll
                for (int c = 0; c < 4; ++c) r[c] = (u0[c] * w0 + u1[c] * w1) * scl;
                ((f32x4*)orows)[vec] = r;
            }
        }
    }
}

extern "C" void kernel_launch(void* const* d_in, const int* in_sizes, int n_in,
                              void* d_out, int out_size, void* d_ws, size_t ws_size,
                              hipStream_t stream)
{
    const float* q  = (const float*)d_in[0];
    const float* k  = (const float*)d_in[1];
    const float* v  = (const float*)d_in[2];
    const float* sm = (const float*)d_in[3];

    if (ws_size < (size_t)50857000) return;
    char* ws = (char*)d_ws;
    // layout: kq 16MB | vT 16MB | ks 256KB | vab/tickets (2KB, zeroed) | ml 448KB | U1 14MB
    unsigned short* kq = (unsigned short*)(ws);
    unsigned short* vT = (unsigned short*)(ws + (1u << 24));
    float*          ks = (float*)(ws + (2u << 24));
    unsigned int*  vab = (unsigned int*)(ws + (2u << 24) + 262144);
    unsigned int* tick = (unsigned int*)(ws + (2u << 24) + 263168);
    float2*         ml = (float2*)(ws + (2u << 24) + 264192);
    float*          U1 = (float*)(ws + (2u << 24) + 1048576);   // ends at 49,283,072
    float*         out = (float*)d_out;

    hipFuncSetAttribute((const void*)attn_kernel,
                        hipFuncAttributeMaxDynamicSharedMemorySize, 73728);

    hipMemsetAsync(ws + (2u << 24) + 262144, 0, 2048, stream);   // vab + tickets
    quant_kv_kernel<<<dim3(8448), dim3(256), 0, stream>>>(k, v, kq, ks, vab);
    vtq_kernel<<<dim3(1024), dim3(256), 0, stream>>>(v, vab, vT);
    attn_kernel<<<dim3(736), dim3(512), 73728, stream>>>(q, kq, vT, ks, vab, sm,
                                                         out, U1, ml, tick);
}

// Round 12
// 137.777 us; speedup vs baseline: 1.5893x; 1.5893x over previous
//
#include <hip/hip_runtime.h>

#define S_LEN 2048
#define D_DIM 128
#define NBH   32
#define LOG2E 1.44269504f
#define NEGM  -1000000.0f

typedef __bf16 bf16x8 __attribute__((ext_vector_type(8)));
typedef short  s16x8  __attribute__((ext_vector_type(8)));
typedef float  f32x4  __attribute__((ext_vector_type(4)));
typedef float  f32x16 __attribute__((ext_vector_type(16)));
typedef unsigned int u32x4 __attribute__((ext_vector_type(4)));
typedef unsigned int u32x2 __attribute__((ext_vector_type(2)));

static __device__ __forceinline__ unsigned short f32_to_bf16_bits_exact(float f) {
    return (unsigned short)(__float_as_uint(f) >> 16);   // exact for small ints
}
static __device__ __forceinline__ float round_away(float t) {
    float r = floorf(fabsf(t) + 0.5f);
    return (t >= 0.0f) ? r : -r;
}
// p0,p1 -> one u32 of two bf16(floor(fma(p,127,0.5))) via v_perm
static __device__ __forceinline__ unsigned int pq_pack(float p0, float p1) {
    float a = floorf(fmaf(p0, 127.0f, 0.5f));
    float b = floorf(fmaf(p1, 127.0f, 0.5f));
    return __builtin_amdgcn_perm(__float_as_uint(b), __float_as_uint(a), 0x07060302);
}

// ------- fused: per-token quant of K (blocks 0..8191) + V amax (8192..) ----
__global__ __launch_bounds__(256) void quant_kv_kernel(
    const float* __restrict__ k, const float* __restrict__ v,
    unsigned short* __restrict__ kq, float* __restrict__ ks,
    unsigned int* __restrict__ vab)
{
    if (blockIdx.x < 8192) {
        int row = blockIdx.x * 8 + (threadIdx.x >> 5);
        int l32 = threadIdx.x & 31;
        size_t base = (size_t)row * D_DIM + l32 * 4;
        float4 x = *(const float4*)(k + base);
        float amax = fmaxf(fmaxf(fabsf(x.x), fabsf(x.y)), fmaxf(fabsf(x.z), fabsf(x.w)));
        #pragma unroll
        for (int m = 1; m < 32; m <<= 1) amax = fmaxf(amax, __shfl_xor(amax, m));
        float scale = fmaxf(amax, 1e-8f) / 127.0f;
        ushort4 o;
        o.x = f32_to_bf16_bits_exact(fminf(fmaxf(round_away(x.x / scale), -127.0f), 127.0f));
        o.y = f32_to_bf16_bits_exact(fminf(fmaxf(round_away(x.y / scale), -127.0f), 127.0f));
        o.z = f32_to_bf16_bits_exact(fminf(fmaxf(round_away(x.z / scale), -127.0f), 127.0f));
        o.w = f32_to_bf16_bits_exact(fminf(fmaxf(round_away(x.w / scale), -127.0f), 127.0f));
        *(ushort4*)(kq + base) = o;
        if (l32 == 0) ks[row] = scale;
    } else {
        int bid2 = blockIdx.x - 8192;
        int bh = bid2 >> 3, blk = bid2 & 7;
        const float4* base = (const float4*)(v + (size_t)bh * S_LEN * D_DIM) + blk * 8192;
        int t = threadIdx.x;
        float am = 0.0f;
        #pragma unroll
        for (int i = 0; i < 32; ++i) {
            float4 x = base[t + i * 256];
            am = fmaxf(am, fmaxf(fmaxf(fabsf(x.x), fabsf(x.y)), fmaxf(fabsf(x.z), fabsf(x.w))));
        }
        #pragma unroll
        for (int m = 1; m < 64; m <<= 1) am = fmaxf(am, __shfl_xor(am, m));
        __shared__ float red[4];
        if ((t & 63) == 0) red[t >> 6] = am;
        __syncthreads();
        if (t == 0) {
            float a = fmaxf(fmaxf(red[0], red[1]), fmaxf(red[2], red[3]));
            atomicMax(&vab[bh], __float_as_uint(a));
        }
    }
}

// ---------------- V quantize + transpose to [B,H,D,S] ----------------------
__global__ __launch_bounds__(256) void vtq_kernel(const float* __restrict__ v,
                                                  const unsigned int* __restrict__ vab,
                                                  unsigned short* __restrict__ vT)
{
    __shared__ unsigned short tileT[128][72];
    int bh = blockIdx.x >> 5, sb = blockIdx.x & 31;
    float scale = fmaxf(__uint_as_float(vab[bh]), 1e-8f) / 127.0f;
    int t = threadIdx.x;
    const float* src = v + ((size_t)bh * S_LEN + sb * 64) * D_DIM;
    #pragma unroll
    for (int it = 0; it < 8; ++it) {
        int c = t + it * 256;
        int rs = c >> 5, c4 = (c & 31) * 4;
        float4 x = *(const float4*)(src + rs * D_DIM + c4);
        float vals[4] = {x.x, x.y, x.z, x.w};
        #pragma unroll
        for (int u = 0; u < 4; ++u) {
            float r = fminf(fmaxf(round_away(vals[u] / scale), -127.0f), 127.0f);
            tileT[c4 + u][rs] = f32_to_bf16_bits_exact(r);
        }
    }
    __syncthreads();
    unsigned short* dst = vT + (size_t)bh * D_DIM * S_LEN + sb * 64;
    #pragma unroll
    for (int it = 0; it < 4; ++it) {
        int c = t + it * 256;
        int d = c >> 3, c8 = (c & 7) * 8;
        *(s16x8*)(dst + (size_t)d * S_LEN + c8) = *(const s16x8*)&tileT[d][c8];
    }
}

// -------- int8 flash attention: key-split chunks, NO cross-WG sync ---------
// Grid 736 WGs, LPT order. qb<=8 whole; qb in [9,15] split into 2 chunks of
// (qb+1) key-tiles. Chunk0 -> U0 in out rows; chunk1 -> U1 + (m,l) in ws.
// Pair merge happens in a separate kernel (kernel boundary = visibility).
__global__ __launch_bounds__(512, 4) void attn_kernel(
    const float* __restrict__ qsrc,
    const unsigned short* __restrict__ kq,
    const unsigned short* __restrict__ vT,
    const float* __restrict__ ks,
    const unsigned int* __restrict__ vab,
    const float* __restrict__ smp,
    float* __restrict__ out,
    float* __restrict__ U1,
    float2* __restrict__ mlbuf)
{
    extern __shared__ char smem[];

    const int tid  = threadIdx.x;
    const int lane = tid & 63;
    const int wid  = tid >> 6;       // 0..7
    const int w4   = wid & 3;
    const int half = wid >> 2;       // key-column half
    const int c32  = lane & 31;
    const int hi   = lane >> 5;
    const int t8   = tid & 255;

    char*   KbH  = smem + half * 8192;
    char*   VbH  = smem + 16384 + half * 8192;
    float*  ksl  = (float*)(smem + 32768);
    float2* ML   = (float2*)(smem + 34816);   // used only AFTER the K-loop
    char*   Qlds = smem + 40960;
    float*  Ol   = (float*)smem;

    // ---- LPT schedule decode: lengths desc (18,16,15,...,2) ----
    int rem = (int)blockIdx.x, qb = 0, chunk = -1, bh = 0;
    {
        bool fnd = false;
        for (int L = 18; L >= 2 && !fnd; --L) {
            if (L >= 10 && L <= 16) {                 // chunk entries, qb = L-1
                if (rem < 64) { qb = L - 1; chunk = rem >> 5; bh = rem & 31; fnd = true; }
                else rem -= 64;
            }
            if (!fnd && !(L & 1)) {                   // unsplit entries, jn = L
                int qu = (L >> 1) - 1;
                if (qu <= 8) {
                    if (rem < 32) { qb = qu; chunk = -1; bh = rem & 31; fnd = true; }
                    else rem -= 32;
                }
            }
        }
    }
    int j0 = 0, jEnd = 2 * qb + 2;
    if (chunk == 0) jEnd = qb + 1;
    else if (chunk == 1) j0 = qb + 1;
    const int pair = (qb - 9) * 32 + bh;              // valid when chunk >= 0

    const float qk_scale = smp[0] * LOG2E;
    const float vscale   = fmaxf(__uint_as_float(vab[bh]), 1e-8f) / 127.0f;
    const float vs_term  = vscale / 127.0f;

    const char* kqb = (const char*)(kq + (size_t)bh * S_LEN * D_DIM);
    const char* vtb = (const char*)(vT + (size_t)bh * D_DIM * S_LEN);

    // ---- prologue: ks row + in-kernel Q quantization into Qlds ----
    // qsl lives in the Kb region (smem+0): prologue-only, consumed into the
    // qf register before the loop's first barrier (after which Kb is reused).
    ((f32x4*)ksl)[tid] = ((const f32x4*)(ks + (size_t)bh * S_LEN))[tid];
    float* qsl = (float*)smem;
    {
        const float* qg = qsrc + ((size_t)bh * S_LEN + qb * 128) * D_DIM;
        int l32 = tid & 31;
        #pragma unroll
        for (int p = 0; p < 8; ++p) {
            int row = p * 16 + (tid >> 5);
            f32x4 x = *(const f32x4*)(qg + (size_t)row * D_DIM + l32 * 4);
            float am = fmaxf(fmaxf(fabsf(x[0]), fabsf(x[1])), fmaxf(fabsf(x[2]), fabsf(x[3])));
            #pragma unroll
            for (int m = 1; m < 32; m <<= 1) am = fmaxf(am, __shfl_xor(am, m));
            float scale = fmaxf(am, 1e-8f) / 127.0f;
            if (l32 == 0) qsl[row] = scale;
            unsigned short b0 = f32_to_bf16_bits_exact(fminf(fmaxf(round_away(x[0] / scale), -127.0f), 127.0f));
            unsigned short b1 = f32_to_bf16_bits_exact(fminf(fmaxf(round_away(x[1] / scale), -127.0f), 127.0f));
            unsigned short b2 = f32_to_bf16_bits_exact(fminf(fmaxf(round_away(x[2] / scale), -127.0f), 127.0f));
            unsigned short b3 = f32_to_bf16_bits_exact(fminf(fmaxf(round_away(x[3] / scale), -127.0f), 127.0f));
            u32x2 pk; pk.x = (unsigned int)b0 | ((unsigned int)b1 << 16);
            pk.y = (unsigned int)b2 | ((unsigned int)b3 << 16);
            int base = (row & 3) * 8192 + (row >> 2) * 256;
            int off  = (l32 * 8) ^ (((row >> 2) & 15) << 4);
            *(u32x2*)(Qlds + base + off) = pk;
        }
    }
    __syncthreads();
    const int   q  = qb * 128 + c32 * 4 + w4;
    const float qf = qsl[c32 * 4 + w4] * qk_scale;   // register before first B1

    // per-thread staging offsets (constant over j): linear LDS, pre-swz global
    int kOff[2], vOff[2], lOff[2];
    #pragma unroll
    for (int it = 0; it < 2; ++it) {
        int L = (t8 + it * 256) * 16;
        lOff[it] = L;
        int r = L >> 8, x = L & 255;
        int c = x ^ ((r & 15) << 4);
        kOff[it] = (half * 32 + r) * 256 + c;
        vOff[it] = ((c >> 6) * 32 + r) * (S_LEN * 2) + half * 64 + (c & 63);
    }

    float mrow = -100.0f;            // finite sentinel; real scores are O(1)
    float lrow = 0.0f;
    f32x16 oacc0, oacc1, oacc2, oacc3;
    #pragma unroll
    for (int i = 0; i < 16; ++i) { oacc0[i] = 0.f; oacc1[i] = 0.f; oacc2[i] = 0.f; oacc3[i] = 0.f; }

    const int swz = (c32 & 15) << 4;
    const char* aBase = KbH + c32 * 256;
    const char* bBase = Qlds + w4 * 8192 + c32 * 256;
    const char* vBase = VbH + c32 * 256;

    for (int j = j0; j < jEnd; ++j) {
        const int jb = j * 64;
        s16x8 kr0 = *(const s16x8*)(kqb + jb * 256 + kOff[0]);
        s16x8 kr1 = *(const s16x8*)(kqb + jb * 256 + kOff[1]);
        s16x8 vr0 = *(const s16x8*)(vtb + jb * 2   + vOff[0]);
        s16x8 vr1 = *(const s16x8*)(vtb + jb * 2   + vOff[1]);
        __syncthreads();                 // B1: previous tile's readers done
        *(s16x8*)(KbH + lOff[0]) = kr0;
        *(s16x8*)(KbH + lOff[1]) = kr1;
        *(s16x8*)(VbH + lOff[0]) = vr0;
        *(s16x8*)(VbH + lOff[1]) = vr1;
        __syncthreads();                 // B2: tile ready

        // ---- swapped QK^T: S^T = K_half · Q^T ----
        f32x16 sc;
        #pragma unroll
        for (int i = 0; i < 16; ++i) sc[i] = 0.f;
        #pragma unroll
        for (int st = 0; st < 8; ++st) {
            int cB = (st * 32 + hi * 16) ^ swz;
            bf16x8 a = __builtin_bit_cast(bf16x8, *(const s16x8*)(aBase + cB));
            bf16x8 b = __builtin_bit_cast(bf16x8, *(const s16x8*)(bBase + cB));
            sc = __builtin_amdgcn_mfma_f32_32x32x16_bf16(a, b, sc, 0, 0, 0);
        }

        // ---- dequant folded with -mrow: t = fma(s_int, qf*kv, -mrow) ----
        const int  jbh = jb + half * 32;
        const bool need_mask = (jbh + 31 > qb * 128 + w4);
        float mhA = -3.0e38f, mhB = -3.0e38f;
        #pragma unroll
        for (int gg = 0; gg < 4; ++gg) {
            f32x4 kv = *(const f32x4*)&ksl[jbh + gg * 8 + hi * 4];
            #pragma unroll
            for (int i = 0; i < 4; ++i) {
                int r = gg * 4 + i;
                float c  = qf * kv[i];
                float tv = fmaf(sc[r], c, -mrow);
                if (need_mask) tv = (q >= jbh + gg * 8 + i + hi * 4) ? tv : NEGM;
                sc[r] = tv;
                if (i & 1) mhB = fmaxf(mhB, tv);
                else       mhA = fmaxf(mhA, tv);
            }
        }
        float mh     = fmaxf(mhA, mhB);
        float vmax_t = fmaxf(mh, __shfl_xor(mh, 32));

        // ---- defer-max (THR=1): rescale only when row max grew by > 1 ----
        if (__any(vmax_t > 1.0f)) {
            float sh    = fmaxf(vmax_t, 0.0f);
            float alpha = exp2f(-sh);
            mrow += sh;
            #pragma unroll
            for (int r = 0; r < 16; ++r) sc[r] -= sh;
            oacc0 *= alpha; oacc1 *= alpha; oacc2 *= alpha; oacc3 *= alpha;
            lrow  *= alpha;
        }

        // ---- p = exp2(t) in place (p <= 2, p_q <= 254: bf16-exact) ----
        float ts[8];
        #pragma unroll
        for (int r = 0; r < 8; ++r) {
            sc[r]     = exp2f(sc[r]);
            sc[r + 8] = exp2f(sc[r + 8]);
            ts[r] = sc[r] + sc[r + 8];
        }
        #pragma unroll
        for (int stp = 4; stp >= 1; stp >>= 1)
            #pragma unroll
            for (int r = 0; r < stp; ++r) ts[r] += ts[r + stp];
        lrow += ts[0] + __shfl_xor(ts[0], 32);

        // ---- pack p_q (bf16), cross-half swap, PV: 8 MFMA ----
        unsigned int W[8];
        #pragma unroll
        for (int gg = 0; gg < 4; ++gg) {
            W[gg*2+0] = pq_pack(sc[gg*4+0], sc[gg*4+1]);
            W[gg*2+1] = pq_pack(sc[gg*4+2], sc[gg*4+3]);
        }
        #pragma unroll
        for (int s = 0; s < 2; ++s) {
            asm("v_permlane32_swap_b32 %0, %1" : "+v"(W[s*4+0]), "+v"(W[s*4+2]));
            asm("v_permlane32_swap_b32 %0, %1" : "+v"(W[s*4+1]), "+v"(W[s*4+3]));
        }
        #pragma unroll
        for (int s = 0; s < 2; ++s) {
            u32x4 uw; uw.x = W[s*4+0]; uw.y = W[s*4+1]; uw.z = W[s*4+2]; uw.w = W[s*4+3];
            bf16x8 bfrag = __builtin_bit_cast(bf16x8, uw);
            int cb = s * 32 + hi * 16;
            bf16x8 va;
            va = __builtin_bit_cast(bf16x8, *(const s16x8*)(vBase + ((cb +   0) ^ swz)));
            oacc0 = __builtin_amdgcn_mfma_f32_32x32x16_bf16(va, bfrag, oacc0, 0, 0, 0);
            va = __builtin_bit_cast(bf16x8, *(const s16x8*)(vBase + ((cb +  64) ^ swz)));
            oacc1 = __builtin_amdgcn_mfma_f32_32x32x16_bf16(va, bfrag, oacc1, 0, 0, 0);
            va = __builtin_bit_cast(bf16x8, *(const s16x8*)(vBase + ((cb + 128) ^ swz)));
            oacc2 = __builtin_amdgcn_mfma_f32_32x32x16_bf16(va, bfrag, oacc2, 0, 0, 0);
            va = __builtin_bit_cast(bf16x8, *(const s16x8*)(vBase + ((cb + 192) ^ swz)));
            oacc3 = __builtin_amdgcn_mfma_f32_32x32x16_bf16(va, bfrag, oacc3, 0, 0, 0);
        }
    }

    // ---- merge the two key-halves: exchange (m, l) via LDS ----
    __syncthreads();
    if (hi == 0) { float2 ml2; ml2.x = mrow; ml2.y = lrow; ML[half * 128 + w4 * 32 + c32] = ml2; }
    __syncthreads();
    float2 mo  = ML[(1 - half) * 128 + w4 * 32 + c32];
    float  mfin = fmaxf(mrow, mo.x);
    float  bs  = exp2f(mrow - mfin);       // own scale (~0 if this half all-masked)
    float  bo  = exp2f(mo.x - mfin);
    float  lfin = lrow * bs + mo.y * bo;

    // chunk partial bookkeeping: per-row (m, l), written once (half0, hi0)
    if (chunk >= 0 && half == 0 && hi == 0) {
        float2 t; t.x = mfin; t.y = lfin;
        mlbuf[(size_t)pair * 256 + chunk * 128 + (c32 * 4 + w4)] = t;
    }

    const float inv = (chunk < 0) ? (bs * vs_term / lfin) : bs;
    float* dstBase = (chunk == 1) ? (U1 + (size_t)pair * 16384)
                                  : (out + ((size_t)bh * S_LEN + qb * 128) * D_DIM);

    // ---- epilogue: O^T -> LDS transpose -> coalesced stores ----
    for (int pass = 0; pass < 2; ++pass) {
        __syncthreads();
        if (half == 0 && (w4 >> 1) == pass) {
            float* reg = Ol + (w4 & 1) * 4224 + c32 * 132;
            #pragma unroll
            for (int r = 0; r < 16; ++r) {
                int drow = (r & 3) + 8 * (r >> 2) + 4 * hi;
                reg[drow]      = oacc0[r] * inv;
                reg[drow + 32] = oacc1[r] * inv;
                reg[drow + 64] = oacc2[r] * inv;
                reg[drow + 96] = oacc3[r] * inv;
            }
        }
        __syncthreads();
        if (half == 1 && (w4 >> 1) == pass) {
            float* reg = Ol + (w4 & 1) * 4224 + c32 * 132;
            #pragma unroll
            for (int r = 0; r < 16; ++r) {
                int drow = (r & 3) + 8 * (r >> 2) + 4 * hi;
                reg[drow]      += oacc0[r] * inv;
                reg[drow + 32] += oacc1[r] * inv;
                reg[drow + 64] += oacc2[r] * inv;
                reg[drow + 96] += oacc3[r] * inv;
            }
        }
        __syncthreads();
        #pragma unroll
        for (int it = 0; it < 4; ++it) {
            int idx = tid + it * 512;
            int w2  = idx >> 10;
            int rem2 = idx & 1023;
            int row = rem2 >> 5, c4 = rem2 & 31;
            f32x4 v4 = *(const f32x4*)(Ol + w2 * 4224 + row * 132 + c4 * 4);
            int lr = row * 4 + pass * 2 + w2;
            *(f32x4*)(dstBase + (size_t)lr * D_DIM + c4 * 4) = v4;
        }
    }
}

// ------------- pair merge: out[rows] = (U0*w0 + U1*w1) * vs/l ---------------
__global__ __launch_bounds__(256) void merge_kernel(
    float* __restrict__ out, const float* __restrict__ U1,
    const float2* __restrict__ mlbuf, const unsigned int* __restrict__ vab)
{
    int pair = blockIdx.x >> 1;
    int hseg = blockIdx.x & 1;              // rows [hseg*64, hseg*64+64)
    int qb = (pair >> 5) + 9, bh = pair & 31;
    float vscale  = fmaxf(__uint_as_float(vab[bh]), 1e-8f) / 127.0f;
    float vs_term = vscale / 127.0f;
    const float2* mp = mlbuf + (size_t)pair * 256;
    float* orows = out + ((size_t)bh * S_LEN + qb * 128 + hseg * 64) * D_DIM;
    const float* U1p = U1 + (size_t)pair * 16384 + hseg * 64 * D_DIM;
    int t = threadIdx.x;
    #pragma unroll
    for (int it = 0; it < 8; ++it) {
        int vec = t + it * 256;             // 2048 f32x4 = 64 rows x 32
        int row = vec >> 5;
        float2 a = mp[hseg * 64 + row], b = mp[128 + hseg * 64 + row];
        float ms = fmaxf(a.x, b.x);
        float w0 = exp2f(a.x - ms), w1 = exp2f(b.x - ms);
        float scl = vs_term / (w0 * a.y + w1 * b.y);
        f32x4 u0 = ((const f32x4*)orows)[vec];
        f32x4 u1 = ((const f32x4*)U1p)[vec];
        f32x4 r;
        #pragma unroll
        for (int c = 0; c < 4; ++c) r[c] = (u0[c] * w0 + u1[c] * w1) * scl;
        ((f32x4*)orows)[vec] = r;
    }
}

extern "C" void kernel_launch(void* const* d_in, const int* in_sizes, int n_in,
                              void* d_out, int out_size, void* d_ws, size_t ws_size,
                              hipStream_t stream)
{
    const float* q  = (const float*)d_in[0];
    const float* k  = (const float*)d_in[1];
    const float* v  = (const float*)d_in[2];
    const float* sm = (const float*)d_in[3];

    if (ws_size < (size_t)50857000) return;
    char* ws = (char*)d_ws;
    // layout: kq 16MB | vT 16MB | ks 256KB | vab (zeroed) | ml 448KB | U1 14MB
    unsigned short* kq = (unsigned short*)(ws);
    unsigned short* vT = (unsigned short*)(ws + (1u << 24));
    float*          ks = (float*)(ws + (2u << 24));
    unsigned int*  vab = (unsigned int*)(ws + (2u << 24) + 262144);
    float2*         ml = (float2*)(ws + (2u << 24) + 264192);
    float*          U1 = (float*)(ws + (2u << 24) + 1048576);   // ends at 49,283,072
    float*         out = (float*)d_out;

    hipFuncSetAttribute((const void*)attn_kernel,
                        hipFuncAttributeMaxDynamicSharedMemorySize, 73728);

    hipMemsetAsync(vab, 0, 1024, stream);
    quant_kv_kernel<<<dim3(8448), dim3(256), 0, stream>>>(k, v, kq, ks, vab);
    vtq_kernel<<<dim3(1024), dim3(256), 0, stream>>>(v, vab, vT);
    attn_kernel<<<dim3(736), dim3(512), 73728, stream>>>(q, kq, vT, ks, vab, sm,
                                                         out, U1, ml);
    merge_kernel<<<dim3(448), dim3(256), 0, stream>>>(out, U1, ml, vab);
}

// Round 13
// 115.734 us; speedup vs baseline: 1.8920x; 1.1905x over previous
//
#include <hip/hip_runtime.h>

#define S_LEN 2048
#define D_DIM 128
#define NBH   32
#define LOG2E 1.44269504f
#define NEGM  -1000000.0f

typedef __bf16 bf16x8 __attribute__((ext_vector_type(8)));
typedef short  s16x8  __attribute__((ext_vector_type(8)));
typedef float  f32x4  __attribute__((ext_vector_type(4)));
typedef float  f32x16 __attribute__((ext_vector_type(16)));
typedef unsigned int u32x4 __attribute__((ext_vector_type(4)));

static __device__ __forceinline__ unsigned short f32_to_bf16_bits_exact(float f) {
    return (unsigned short)(__float_as_uint(f) >> 16);   // exact for small ints
}
static __device__ __forceinline__ float round_away(float t) {
    float r = floorf(fabsf(t) + 0.5f);
    return (t >= 0.0f) ? r : -r;
}
// p0,p1 -> one u32 of two bf16(floor(fma(p,127,0.5))) via v_perm
static __device__ __forceinline__ unsigned int pq_pack(float p0, float p1) {
    float a = floorf(fmaf(p0, 127.0f, 0.5f));
    float b = floorf(fmaf(p1, 127.0f, 0.5f));
    return __builtin_amdgcn_perm(__float_as_uint(b), __float_as_uint(a), 0x07060302);
}

// ------- fused: per-token quant of Q,K (blocks 0..16383) + V amax (16384..) -
__global__ __launch_bounds__(256) void quant_qkv_kernel(
    const float* __restrict__ q, const float* __restrict__ k,
    const float* __restrict__ v,
    unsigned short* __restrict__ qq, unsigned short* __restrict__ kq,
    float* __restrict__ qs, float* __restrict__ ks,
    unsigned int* __restrict__ vab)
{
    if (blockIdx.x < 16384) {
        const int R = NBH * S_LEN;
        int w   = blockIdx.x * 8 + (threadIdx.x >> 5);
        int l32 = threadIdx.x & 31;
        const float* src; unsigned short* dq; float* ds; int row;
        if (w < R) { src = q; dq = qq; ds = qs; row = w; }
        else       { src = k; dq = kq; ds = ks; row = w - R; }
        size_t base = (size_t)row * D_DIM + l32 * 4;
        float4 x = *(const float4*)(src + base);
        float amax = fmaxf(fmaxf(fabsf(x.x), fabsf(x.y)), fmaxf(fabsf(x.z), fabsf(x.w)));
        #pragma unroll
        for (int m = 1; m < 32; m <<= 1) amax = fmaxf(amax, __shfl_xor(amax, m));
        float scale = fmaxf(amax, 1e-8f) / 127.0f;
        ushort4 o;
        o.x = f32_to_bf16_bits_exact(fminf(fmaxf(round_away(x.x / scale), -127.0f), 127.0f));
        o.y = f32_to_bf16_bits_exact(fminf(fmaxf(round_away(x.y / scale), -127.0f), 127.0f));
        o.z = f32_to_bf16_bits_exact(fminf(fmaxf(round_away(x.z / scale), -127.0f), 127.0f));
        o.w = f32_to_bf16_bits_exact(fminf(fmaxf(round_away(x.w / scale), -127.0f), 127.0f));
        *(ushort4*)(dq + base) = o;
        if (l32 == 0) ds[row] = scale;
    } else {
        int bid2 = blockIdx.x - 16384;
        int bh = bid2 >> 3, blk = bid2 & 7;
        const float4* base = (const float4*)(v + (size_t)bh * S_LEN * D_DIM) + blk * 8192;
        int t = threadIdx.x;
        float am = 0.0f;
        #pragma unroll
        for (int i = 0; i < 32; ++i) {
            float4 x = base[t + i * 256];
            am = fmaxf(am, fmaxf(fmaxf(fabsf(x.x), fabsf(x.y)), fmaxf(fabsf(x.z), fabsf(x.w))));
        }
        #pragma unroll
        for (int m = 1; m < 64; m <<= 1) am = fmaxf(am, __shfl_xor(am, m));
        __shared__ float red[4];
        if ((t & 63) == 0) red[t >> 6] = am;
        __syncthreads();
        if (t == 0) {
            float a = fmaxf(fmaxf(red[0], red[1]), fmaxf(red[2], red[3]));
            atomicMax(&vab[bh], __float_as_uint(a));
        }
    }
}

// ---------------- V quantize + transpose to [B,H,D,S] ----------------------
__global__ __launch_bounds__(256) void vtq_kernel(const float* __restrict__ v,
                                                  const unsigned int* __restrict__ vab,
                                                  unsigned short* __restrict__ vT)
{
    __shared__ unsigned short tileT[128][72];
    int bh = blockIdx.x >> 5, sb = blockIdx.x & 31;
    float scale = fmaxf(__uint_as_float(vab[bh]), 1e-8f) / 127.0f;
    int t = threadIdx.x;
    const float* src = v + ((size_t)bh * S_LEN + sb * 64) * D_DIM;
    #pragma unroll
    for (int it = 0; it < 8; ++it) {
        int c = t + it * 256;
        int rs = c >> 5, c4 = (c & 31) * 4;
        float4 x = *(const float4*)(src + rs * D_DIM + c4);
        float vals[4] = {x.x, x.y, x.z, x.w};
        #pragma unroll
        for (int u = 0; u < 4; ++u) {
            float r = fminf(fmaxf(round_away(vals[u] / scale), -127.0f), 127.0f);
            tileT[c4 + u][rs] = f32_to_bf16_bits_exact(r);
        }
    }
    __syncthreads();
    unsigned short* dst = vT + (size_t)bh * D_DIM * S_LEN + sb * 64;
    #pragma unroll
    for (int it = 0; it < 4; ++it) {
        int c = t + it * 256;
        int d = c >> 3, c8 = (c & 7) * 8;
        *(s16x8*)(dst + (size_t)d * S_LEN + c8) = *(const s16x8*)&tileT[d][c8];
    }
}

// -------- fused int8 flash attention: 8-wave key-split, swapped 32x32 ------
// LDS map (extern, 73728 B):
//   Kb_h  = smem + h*8192          (2 x 8 KB  : K half-tile, 32 rows x 256B, swz)
//   Vb_h  = smem + 16384 + h*8192  (2 x 8 KB  : V^T half [32 rho][256B], swz)
//   ksl   = smem + 32768           (8 KB      : full ks row)
//   ML    = smem + 34816           (2 KB      : per-half {m,l} for merge)
//   Qlds  = smem + 40960           (32 KB     : Q tile [w4][32 rows][256B], swz)
//   Ol    = smem + 0               (epilogue reuse: 2 x [32][132] f32)
__global__ __launch_bounds__(512, 4) void attn_kernel(
    const unsigned short* __restrict__ qq,
    const unsigned short* __restrict__ kq,
    const unsigned short* __restrict__ vT,
    const float* __restrict__ qs,
    const float* __restrict__ ks,
    const unsigned int* __restrict__ vab,
    const float* __restrict__ smp,
    float* __restrict__ out)
{
    extern __shared__ char smem[];

    const int tid  = threadIdx.x;
    const int lane = tid & 63;
    const int wid  = tid >> 6;       // 0..7
    const int w4   = wid & 3;
    const int half = wid >> 2;       // key-column half
    const int c32  = lane & 31;
    const int hi   = lane >> 5;
    const int t8   = tid & 255;

    char*   KbH  = smem + half * 8192;
    char*   VbH  = smem + 16384 + half * 8192;
    float*  ksl  = (float*)(smem + 32768);
    float2* ML   = (float2*)(smem + 34816);
    char*   Qlds = smem + 40960;
    float*  Ol   = (float*)smem;

    const int bid = blockIdx.x;
    const int g   = bid >> 5;
    const int qb  = (g < 8) ? (15 - g) : (g - 8);  // (bid, bid+256) complementary
    const int bh  = bid & 31;

    const float qk_scale = smp[0] * LOG2E;
    const float vscale   = fmaxf(__uint_as_float(vab[bh]), 1e-8f) / 127.0f;
    const float vs_term  = vscale / 127.0f;

    const int   q  = qb * 128 + c32 * 4 + w4;
    const float qf = qs[(size_t)bh * S_LEN + q] * qk_scale;

    const char* kqb = (const char*)(kq + (size_t)bh * S_LEN * D_DIM);
    const char* vtb = (const char*)(vT + (size_t)bh * D_DIM * S_LEN);

    // ---- prologue staging: ks row (8 KB) + Q tile (32 KB, swizzled) ----
    ((f32x4*)ksl)[tid] = ((const f32x4*)(ks + (size_t)bh * S_LEN))[tid];
    {
        const char* qqb = (const char*)(qq + ((size_t)bh * S_LEN + qb * 128) * D_DIM);
        #pragma unroll
        for (int it = 0; it < 4; ++it) {
            int L = (tid + it * 512) * 16;        // [0, 32768)
            int w = L >> 13, Lw = L & 8191;
            int r = Lw >> 8, x = Lw & 255;
            int col = x ^ ((r & 15) << 4);
            *(s16x8*)(Qlds + L) = *(const s16x8*)(qqb + (r * 4 + w) * 256 + col);
        }
    }

    // per-thread staging offsets (constant over j): linear LDS, pre-swz global
    int kOff[2], vOff[2], lOff[2];
    #pragma unroll
    for (int it = 0; it < 2; ++it) {
        int L = (t8 + it * 256) * 16;             // [0, 8192)
        lOff[it] = L;
        int r = L >> 8, x = L & 255;
        int c = x ^ ((r & 15) << 4);
        kOff[it] = (half * 32 + r) * 256 + c;
        vOff[it] = ((c >> 6) * 32 + r) * (S_LEN * 2) + half * 64 + (c & 63);
    }

    float mrow = -100.0f;            // finite sentinel; real scores are O(1)
    float lrow = 0.0f;
    f32x16 oacc0, oacc1, oacc2, oacc3;
    #pragma unroll
    for (int i = 0; i < 16; ++i) { oacc0[i] = 0.f; oacc1[i] = 0.f; oacc2[i] = 0.f; oacc3[i] = 0.f; }

    const int swz = (c32 & 15) << 4;
    const char* aBase = KbH + c32 * 256;
    const char* bBase = Qlds + w4 * 8192 + c32 * 256;
    const char* vBase = VbH + c32 * 256;

    // one full iteration; domask folds at compile time via inlined constant
    auto iter = [&](const int j, const bool domask) __attribute__((always_inline)) {
        const int jb = j * 64;
        s16x8 kr0 = *(const s16x8*)(kqb + jb * 256 + kOff[0]);
        s16x8 kr1 = *(const s16x8*)(kqb + jb * 256 + kOff[1]);
        s16x8 vr0 = *(const s16x8*)(vtb + jb * 2   + vOff[0]);
        s16x8 vr1 = *(const s16x8*)(vtb + jb * 2   + vOff[1]);
        __syncthreads();                 // B1: previous tile's readers done
        *(s16x8*)(KbH + lOff[0]) = kr0;
        *(s16x8*)(KbH + lOff[1]) = kr1;
        *(s16x8*)(VbH + lOff[0]) = vr0;
        *(s16x8*)(VbH + lOff[1]) = vr1;
        __syncthreads();                 // B2: tile ready

        // ---- swapped QK^T: S^T = K_half · Q^T (Q frags from LDS) ----
        f32x16 sc;
        #pragma unroll
        for (int i = 0; i < 16; ++i) sc[i] = 0.f;
        #pragma unroll
        for (int st = 0; st < 8; ++st) {
            int cB = (st * 32 + hi * 16) ^ swz;
            bf16x8 a = __builtin_bit_cast(bf16x8, *(const s16x8*)(aBase + cB));
            bf16x8 b = __builtin_bit_cast(bf16x8, *(const s16x8*)(bBase + cB));
            sc = __builtin_amdgcn_mfma_f32_32x32x16_bf16(a, b, sc, 0, 0, 0);
        }

        // ---- dequant folded with -mrow: t = fma(s_int, qf*kv, -mrow) ----
        const int jbh = jb + half * 32;
        float mhA = -3.0e38f, mhB = -3.0e38f;
        #pragma unroll
        for (int gg = 0; gg < 4; ++gg) {
            f32x4 kv = *(const f32x4*)&ksl[jbh + gg * 8 + hi * 4];
            #pragma unroll
            for (int i = 0; i < 4; ++i) {
                int r = gg * 4 + i;
                float tv = fmaf(sc[r], qf * kv[i], -mrow);
                if (domask) tv = (q >= jbh + gg * 8 + i + hi * 4) ? tv : NEGM;
                sc[r] = tv;
                if (i & 1) mhB = fmaxf(mhB, tv);
                else       mhA = fmaxf(mhA, tv);
            }
        }
        float mh     = fmaxf(mhA, mhB);
        float vmax_t = fmaxf(mh, __shfl_xor(mh, 32));

        // ---- defer-max (THR=1): rescale only when row max grew by > 1 ----
        if (__any(vmax_t > 1.0f)) {
            float sh    = fmaxf(vmax_t, 0.0f);
            float alpha = exp2f(-sh);
            mrow += sh;
            #pragma unroll
            for (int r = 0; r < 16; ++r) sc[r] -= sh;
            oacc0 *= alpha; oacc1 *= alpha; oacc2 *= alpha; oacc3 *= alpha;
            lrow  *= alpha;
        }

        // ---- p = exp2(t) in place (p <= 2, p_q <= 254: bf16-exact) ----
        float ts[8];
        #pragma unroll
        for (int r = 0; r < 8; ++r) {
            sc[r]     = exp2f(sc[r]);
            sc[r + 8] = exp2f(sc[r + 8]);
            ts[r] = sc[r] + sc[r + 8];
        }
        #pragma unroll
        for (int stp = 4; stp >= 1; stp >>= 1)
            #pragma unroll
            for (int r = 0; r < stp; ++r) ts[r] += ts[r + stp];
        lrow += ts[0] + __shfl_xor(ts[0], 32);

        // ---- pack p_q (bf16), cross-half swap, PV: 8 MFMA ----
        unsigned int W[8];
        #pragma unroll
        for (int gg = 0; gg < 4; ++gg) {
            W[gg*2+0] = pq_pack(sc[gg*4+0], sc[gg*4+1]);
            W[gg*2+1] = pq_pack(sc[gg*4+2], sc[gg*4+3]);
        }
        #pragma unroll
        for (int s = 0; s < 2; ++s) {
            asm("v_permlane32_swap_b32 %0, %1" : "+v"(W[s*4+0]), "+v"(W[s*4+2]));
            asm("v_permlane32_swap_b32 %0, %1" : "+v"(W[s*4+1]), "+v"(W[s*4+3]));
        }
        #pragma unroll
        for (int s = 0; s < 2; ++s) {
            u32x4 uw; uw.x = W[s*4+0]; uw.y = W[s*4+1]; uw.z = W[s*4+2]; uw.w = W[s*4+3];
            bf16x8 bfrag = __builtin_bit_cast(bf16x8, uw);
            int cb = s * 32 + hi * 16;
            bf16x8 va;
            va = __builtin_bit_cast(bf16x8, *(const s16x8*)(vBase + ((cb +   0) ^ swz)));
            oacc0 = __builtin_amdgcn_mfma_f32_32x32x16_bf16(va, bfrag, oacc0, 0, 0, 0);
            va = __builtin_bit_cast(bf16x8, *(const s16x8*)(vBase + ((cb +  64) ^ swz)));
            oacc1 = __builtin_amdgcn_mfma_f32_32x32x16_bf16(va, bfrag, oacc1, 0, 0, 0);
            va = __builtin_bit_cast(bf16x8, *(const s16x8*)(vBase + ((cb + 128) ^ swz)));
            oacc2 = __builtin_amdgcn_mfma_f32_32x32x16_bf16(va, bfrag, oacc2, 0, 0, 0);
            va = __builtin_bit_cast(bf16x8, *(const s16x8*)(vBase + ((cb + 192) ^ swz)));
            oacc3 = __builtin_amdgcn_mfma_f32_32x32x16_bf16(va, bfrag, oacc3, 0, 0, 0);
        }
    };

    // masked lanes exist only for j >= 2*qb (64j+63 > 128qb): peel last 2 iters
    const int jn    = 2 * qb + 2;
    const int jmain = 2 * qb;
    for (int j = 0; j < jmain; ++j) iter(j, false);
    for (int j = jmain; j < jn; ++j) iter(j, true);

    // ---- merge the two key-halves: exchange (m, l) via LDS ----
    __syncthreads();
    if (hi == 0) { float2 ml2; ml2.x = mrow; ml2.y = lrow; ML[half * 128 + w4 * 32 + c32] = ml2; }
    __syncthreads();
    float2 mo  = ML[(1 - half) * 128 + w4 * 32 + c32];
    float  mfin = fmaxf(mrow, mo.x);
    float  bs  = exp2f(mrow - mfin);       // own scale (~0 if this half all-masked)
    float  bo  = exp2f(mo.x - mfin);
    float  lfin = lrow * bs + mo.y * bo;
    const float inv = bs * vs_term / lfin;

    // ---- epilogue: half0 writes scaled O^T, half1 adds, block stores ----
    for (int pass = 0; pass < 2; ++pass) {
        __syncthreads();
        if (half == 0 && (w4 >> 1) == pass) {
            float* reg = Ol + (w4 & 1) * 4224 + c32 * 132;
            #pragma unroll
            for (int r = 0; r < 16; ++r) {
                int drow = (r & 3) + 8 * (r >> 2) + 4 * hi;
                reg[drow]      = oacc0[r] * inv;
                reg[drow + 32] = oacc1[r] * inv;
                reg[drow + 64] = oacc2[r] * inv;
                reg[drow + 96] = oacc3[r] * inv;
            }
        }
        __syncthreads();
        if (half == 1 && (w4 >> 1) == pass) {
            float* reg = Ol + (w4 & 1) * 4224 + c32 * 132;
            #pragma unroll
            for (int r = 0; r < 16; ++r) {
                int drow = (r & 3) + 8 * (r >> 2) + 4 * hi;
                reg[drow]      += oacc0[r] * inv;
                reg[drow + 32] += oacc1[r] * inv;
                reg[drow + 64] += oacc2[r] * inv;
                reg[drow + 96] += oacc3[r] * inv;
            }
        }
        __syncthreads();
        #pragma unroll
        for (int it = 0; it < 4; ++it) {
            int idx = tid + it * 512;
            int w2  = idx >> 10;
            int rem = idx & 1023;
            int row = rem >> 5, c4 = rem & 31;
            f32x4 v4 = *(const f32x4*)(Ol + w2 * 4224 + row * 132 + c4 * 4);
            int qr = qb * 128 + row * 4 + pass * 2 + w2;
            *(f32x4*)(out + ((size_t)bh * S_LEN + qr) * D_DIM + c4 * 4) = v4;
        }
    }
}

extern "C" void kernel_launch(void* const* d_in, const int* in_sizes, int n_in,
                              void* d_out, int out_size, void* d_ws, size_t ws_size,
                              hipStream_t stream)
{
    const float* q  = (const float*)d_in[0];
    const float* k  = (const float*)d_in[1];
    const float* v  = (const float*)d_in[2];
    const float* sm = (const float*)d_in[3];

    if (ws_size < (size_t)50857000) return;
    char* ws = (char*)d_ws;
    unsigned short* qq = (unsigned short*)(ws);
    unsigned short* kq = (unsigned short*)(ws + (1u << 24));
    unsigned short* vT = (unsigned short*)(ws + (2u << 24));
    float*          qs = (float*)(ws + (3u << 24));
    float*          ks = (float*)(ws + (3u << 24) + 262144);
    unsigned int*  vab = (unsigned int*)(ws + (3u << 24) + 524288);
    float*         out = (float*)d_out;

    hipFuncSetAttribute((const void*)attn_kernel,
                        hipFuncAttributeMaxDynamicSharedMemorySize, 73728);

    hipMemsetAsync(vab, 0, NBH * sizeof(unsigned int), stream);
    quant_qkv_kernel<<<dim3(16640), dim3(256), 0, stream>>>(q, k, v, qq, kq, qs, ks, vab);
    vtq_kernel<<<dim3(1024), dim3(256), 0, stream>>>(v, vab, vT);
    attn_kernel<<<dim3(512), dim3(512), 73728, stream>>>(qq, kq, vT, qs, ks, vab, sm, out);
}